// Round 3
// baseline (387.581 us; speedup 1.0000x reference)
//
#include <hip/hip_runtime.h>
#include <hip/hip_bf16.h>

// GNN: 2-layer GraphConv (DGL norm='both'), N=100000, E=1600000.
// Round 17: column-sliced layer-1 aggregation. r16 counters: k_agg64 FETCH
// 154.5MB = ~92B/edge of h1 gather misses (12.8MB working set vs 4MB per-XCD
// L2, random src). Fix: h1 stored slice-major [4][N][16] (gemm1 wave wv IS
// the slice); agg runs 4 slices x all nodes with slice = blockIdx&3 so each
// slice is pinned to 2 XCDs (round-robin dispatch) and its 3.2MB plane stays
// L2-resident. csrc re-read per slice (4x6.4MB, nontemporal) + h1 2x12.8MB
// -> predicted FETCH ~55MB. x2 slice-major [4][N][16] (nt stores); gemm2
// load remapped. Everything else from r16 (zero-atomic CSR build) unchanged.

#define BSH 7                 // 128 nodes per bucket
#define BNODES 128
#define SRCMASK 0x1FFFF       // src < 131072
#define CAP 2560              // csrc bucket capacity (mean 2048, sigma~45)
#define CHUNK 4096            // edges per place-block (391 blocks)

typedef float f4v __attribute__((ext_vector_type(4)));

__device__ __forceinline__ unsigned short f2bf(float f) {
    unsigned int u = __float_as_uint(f);
    return (unsigned short)((u + 0x7FFFu + ((u >> 16) & 1u)) >> 16);  // RNE
}

// ---------------- place: block-local dual counting sort ---------------------
__global__ __launch_bounds__(1024) void k_place(const int* __restrict__ src,
        const int* __restrict__ dst, int* __restrict__ ebuf,
        unsigned char* __restrict__ sbuf, int* __restrict__ offs,
        int* __restrict__ soffs, int E) {
    __shared__ int lh[800], s[800];
    int t = threadIdx.x;
    int e0 = blockIdx.x * CHUNK;
    int e1 = min(e0 + CHUNK, E);
    if (t < 800) lh[t] = 0;
    __syncthreads();
    for (int i = e0 + t; i < e1; i += 1024) {
        atomicAdd(&lh[dst[i] >> BSH], 0x10000);
        atomicAdd(&lh[src[i] >> BSH], 1);
    }
    __syncthreads();
    if (t < 800) s[t] = lh[t];
    __syncthreads();
    for (int o = 1; o < 800; o <<= 1) {            // packed inclusive scan
        int u = (t < 800 && t >= o) ? s[t - o] : 0;
        __syncthreads();
        if (t < 800) s[t] += u;
        __syncthreads();
    }
    int obase = blockIdx.x * 801;
    if (t < 800) {
        int incl = s[t], c = lh[t];
        int bd = (incl >> 16) - (c >> 16);         // exclusive dst base
        int bs = (incl & 0xFFFF) - (c & 0xFFFF);   // exclusive src base
        offs[obase + t] = bd;
        soffs[obase + t] = bs;
        s[t] = (bd << 16) | bs;                    // packed cursors
    }
    if (t == 0) { offs[obase + 800] = e1 - e0; soffs[obase + 800] = e1 - e0; }
    __syncthreads();
    for (int i = e0 + t; i < e1; i += 1024) {
        int sv = src[i], d = dst[i];               // L2-hot from phase 1
        int pd = atomicAdd(&s[d >> BSH], 0x10000) >> 16;
        ebuf[e0 + pd] = sv | ((d & (BNODES - 1)) << 17);
        int ps = atomicAdd(&s[sv >> BSH], 1) & 0xFFFF;
        sbuf[e0 + ps] = (unsigned char)(sv & (BNODES - 1));
    }
}

// ---------------- sort2: segments -> CSR + nI + nO (no global atomics) ------
__global__ __launch_bounds__(1024) void k_sort2(const int* __restrict__ ebuf,
        const unsigned char* __restrict__ sbuf, const int* __restrict__ offs,
        const int* __restrict__ soffs, int* __restrict__ csrc,
        int* __restrict__ ostart, int* __restrict__ oend,
        float* __restrict__ nI, float* __restrict__ nO, int n, int NBLK) {
    __shared__ int cnt[BNODES], cur[BNODES], s[BNODES], scnt[BNODES];
    __shared__ int segst[400], segen[400], sst[400], sen[400];
    int t = threadIdx.x, b = blockIdx.x;
    if (t < NBLK) {
        segst[t] = t * CHUNK + offs[t * 801 + b];
        segen[t] = t * CHUNK + offs[t * 801 + b + 1];
        sst[t]   = t * CHUNK + soffs[t * 801 + b];
        sen[t]   = t * CHUNK + soffs[t * 801 + b + 1];
    }
    if (t < BNODES) { cnt[t] = 0; scnt[t] = 0; }
    __syncthreads();
    int grp = t >> 3, ln = t & 7;                  // 128 groups x 8 lanes
    for (int sg = grp; sg < NBLK; sg += 128) {
        int en = segen[sg];
        for (int i = segst[sg] + ln; i < en; i += 8)
            atomicAdd(&cnt[ebuf[i] >> 17], 1);
        int en2 = sen[sg];
        for (int i = sst[sg] + ln; i < en2; i += 8)
            atomicAdd(&scnt[sbuf[i]], 1);
    }
    __syncthreads();
    if (t < BNODES) s[t] = cnt[t];
    __syncthreads();
    for (int o = 1; o < BNODES; o <<= 1) {
        int u = (t < BNODES && t >= o) ? s[t - o] : 0;
        __syncthreads();
        if (t < BNODES) s[t] += u;
        __syncthreads();
    }
    if (t < BNODES) {
        int e0 = b * CAP;
        int st = e0 + s[t] - cnt[t];
        cur[t] = st;
        int g = b * BNODES + t;
        if (g < n) {
            ostart[g] = st;
            oend[g] = e0 + s[t];
            nI[g] = rsqrtf(fmaxf((float)cnt[t], 1.0f));
            nO[g] = rsqrtf(fmaxf((float)scnt[t], 1.0f));
        }
    }
    __syncthreads();
    for (int sg = grp; sg < NBLK; sg += 128) {
        int en = segen[sg];
        for (int i = segst[sg] + ln; i < en; i += 8) {
            int p = ebuf[i];                       // L2-hot from pass 1
            int pos = atomicAdd(&cur[p >> 17], 1);
            csrc[pos] = p & SRCMASK;
        }
    }
}

// ---------------- GEMM1: h1(bf16, slice-major [4][N][16]) -------------------
__global__ __launch_bounds__(256) void k_gemm1(const float* __restrict__ x,
                        const float* __restrict__ W1, const float* __restrict__ nO,
                        unsigned short* __restrict__ h1, int n) {
    __shared__ float sX[64 * 132];
    __shared__ float sW[128 * 64];
    const int t = threadIdx.x;
    {
        const float4* W4 = (const float4*)W1;
        float4* sW4 = (float4*)sW;
#pragma unroll
        for (int i = 0; i < 8; i++) sW4[t + 256 * i] = W4[t + 256 * i];
    }
    const int rowbase = blockIdx.x * 64;
    {
        const float4* x4 = (const float4*)x;
        float4* sX4 = (float4*)sX;
#pragma unroll
        for (int i = 0; i < 8; i++) {
            int f = t + 256 * i;
            int row = f >> 5, kc = f & 31;
            int grow = rowbase + row;
            float4 v = make_float4(0.f, 0.f, 0.f, 0.f);
            if (grow < n) v = x4[(size_t)grow * 32 + kc];
            sX4[row * 33 + kc] = v;
        }
    }
    __syncthreads();
    const int lane = t & 63, wv = t >> 6;
    const int rg = lane >> 2, cg = lane & 3;
    const int c0 = wv * 16 + cg * 4;
    float acc[4][4] = {};
    for (int kk = 0; kk < 128; kk += 4) {
        float xr[4][4], wr[4][4];
#pragma unroll
        for (int i = 0; i < 4; i++)
            *(float4*)xr[i] = *(const float4*)&sX[(rg + 16 * i) * 132 + kk];
#pragma unroll
        for (int j = 0; j < 4; j++)
            *(float4*)wr[j] = *(const float4*)&sW[(kk + j) * 64 + c0];
#pragma unroll
        for (int j = 0; j < 4; j++)
#pragma unroll
            for (int i = 0; i < 4; i++)
#pragma unroll
                for (int c = 0; c < 4; c++)
                    acc[i][c] = fmaf(xr[i][j], wr[j][c], acc[i][c]);
    }
    const size_t pl = (size_t)n * 16;              // slice plane (ushorts)
#pragma unroll
    for (int i = 0; i < 4; i++) {
        int grow = rowbase + rg + 16 * i;
        if (grow < n) {
            float nf = nO[grow];
            ushort4 o;
            o.x = f2bf(acc[i][0] * nf); o.y = f2bf(acc[i][1] * nf);
            o.z = f2bf(acc[i][2] * nf); o.w = f2bf(acc[i][3] * nf);
            // slice = wv (c0>>4), in-slice col = cg*4 (c0&15)
            *(ushort4*)&h1[(size_t)wv * pl + (size_t)grow * 16 + cg * 4] = o;
        }
    }
}

// ---------------- agg1 sliced: slice=blockIdx&3 -> 2 XCDs, L2-resident ------
// Wave = node. 16 subs x 4 col-lanes; uint2 = 4 bf16 cols per lane per edge.
// csrc nontemporal (streaming, don't evict the h1 slice); x2 nt stores.
__global__ void k_agg64s(const unsigned short* __restrict__ h,
                         const int* __restrict__ csrc,
                         const int* __restrict__ ostart, const int* __restrict__ oend,
                         const float* __restrict__ nI, const float* __restrict__ b1,
                         float* __restrict__ x2, int n) {
    const int s = blockIdx.x & 3;                  // slice; XCD s / s+4
    const int node = (blockIdx.x >> 2) * 4 + (threadIdx.x >> 6);
    const int lane = threadIdx.x & 63;
    if (node >= n) return;
    int s0 = ostart[node], s1 = oend[node];
    const int sub = lane >> 2;                     // 16 edges in flight
    const int cl = lane & 3;                       // 4 cols (one uint2)
    const uint2* hs = (const uint2*)h + (size_t)s * n * 4;  // slice plane
    float a0 = 0.f, a1 = 0.f, a2 = 0.f, a3 = 0.f;
    float d0 = 0.f, d1 = 0.f, d2 = 0.f, d3 = 0.f;
    int e = s0;
    for (; e + 31 < s1; e += 32) {                 // 32 edges, 2 uint2/lane
        int p0 = __builtin_nontemporal_load(csrc + e + sub);
        int p1 = __builtin_nontemporal_load(csrc + e + 16 + sub);
        uint2 u0 = hs[(size_t)p0 * 4 + cl];
        uint2 u1 = hs[(size_t)p1 * 4 + cl];
        a0 += __uint_as_float(u0.x << 16);
        a1 += __uint_as_float(u0.x & 0xFFFF0000u);
        a2 += __uint_as_float(u0.y << 16);
        a3 += __uint_as_float(u0.y & 0xFFFF0000u);
        d0 += __uint_as_float(u1.x << 16);
        d1 += __uint_as_float(u1.x & 0xFFFF0000u);
        d2 += __uint_as_float(u1.y << 16);
        d3 += __uint_as_float(u1.y & 0xFFFF0000u);
    }
    for (; e < s1; e += 16) {                      // tail, guarded
        if (e + sub < s1) {
            int p = __builtin_nontemporal_load(csrc + e + sub);
            uint2 u = hs[(size_t)p * 4 + cl];
            a0 += __uint_as_float(u.x << 16);
            a1 += __uint_as_float(u.x & 0xFFFF0000u);
            a2 += __uint_as_float(u.y << 16);
            a3 += __uint_as_float(u.y & 0xFFFF0000u);
        }
    }
    a0 += d0; a1 += d1; a2 += d2; a3 += d3;
    a0 += __shfl(a0, lane ^ 4, 64);
    a1 += __shfl(a1, lane ^ 4, 64);
    a2 += __shfl(a2, lane ^ 4, 64);
    a3 += __shfl(a3, lane ^ 4, 64);
    a0 += __shfl(a0, lane ^ 8, 64);
    a1 += __shfl(a1, lane ^ 8, 64);
    a2 += __shfl(a2, lane ^ 8, 64);
    a3 += __shfl(a3, lane ^ 8, 64);
    a0 += __shfl(a0, lane ^ 16, 64);
    a1 += __shfl(a1, lane ^ 16, 64);
    a2 += __shfl(a2, lane ^ 16, 64);
    a3 += __shfl(a3, lane ^ 16, 64);
    a0 += __shfl(a0, lane ^ 32, 64);
    a1 += __shfl(a1, lane ^ 32, 64);
    a2 += __shfl(a2, lane ^ 32, 64);
    a3 += __shfl(a3, lane ^ 32, 64);
    if (sub == 0) {
        float ni = nI[node];
        const float* bb = b1 + s * 16 + cl * 4;
        f4v o;
        o[0] = fmaxf(fmaf(a0, ni, bb[0]), 0.f);
        o[1] = fmaxf(fmaf(a1, ni, bb[1]), 0.f);
        o[2] = fmaxf(fmaf(a2, ni, bb[2]), 0.f);
        o[3] = fmaxf(fmaf(a3, ni, bb[3]), 0.f);
        __builtin_nontemporal_store(o,
            (f4v*)(x2 + (size_t)s * n * 16 + (size_t)node * 16 + cl * 4));
    }
}

// ---------------- GEMM2: reads slice-major x2 [4][N][16] --------------------
__global__ __launch_bounds__(256) void k_gemm2(const float* __restrict__ x2,
                        const float* __restrict__ W2, const float* __restrict__ nO,
                        unsigned short* __restrict__ h2, int n) {
    __shared__ float sX[128 * 68];
    __shared__ float sW[64 * 32];
    const int t = threadIdx.x;
    {
        const float4* W4 = (const float4*)W2;
        float4* sW4 = (float4*)sW;
#pragma unroll
        for (int i = 0; i < 2; i++) sW4[t + 256 * i] = W4[t + 256 * i];
    }
    const int rowbase = blockIdx.x * 128;
    const size_t n4 = (size_t)n * 4;               // slice plane in float4
    {
        const float4* x4 = (const float4*)x2;
        float4* sX4 = (float4*)sX;
#pragma unroll
        for (int i = 0; i < 8; i++) {
            int f = t + 256 * i;
            int row = f >> 4, kc = f & 15;
            int grow = rowbase + row;
            float4 v = make_float4(0.f, 0.f, 0.f, 0.f);
            if (grow < n)
                v = x4[(size_t)(kc >> 2) * n4 + (size_t)grow * 4 + (kc & 3)];
            sX4[row * 17 + kc] = v;
        }
    }
    __syncthreads();
    const int lane = t & 63, wv = t >> 6;
    const int whalf = wv >> 1, chalf = wv & 1;
    const int rg = lane >> 2, cg = lane & 3;
    const int c0 = chalf * 16 + cg * 4;
    const int rloc = whalf * 64 + rg;
    float acc[4][4] = {};
    for (int kk = 0; kk < 64; kk += 4) {
        float xr[4][4], wr[4][4];
#pragma unroll
        for (int i = 0; i < 4; i++)
            *(float4*)xr[i] = *(const float4*)&sX[(rloc + 16 * i) * 68 + kk];
#pragma unroll
        for (int j = 0; j < 4; j++)
            *(float4*)wr[j] = *(const float4*)&sW[(kk + j) * 32 + c0];
#pragma unroll
        for (int j = 0; j < 4; j++)
#pragma unroll
            for (int i = 0; i < 4; i++)
#pragma unroll
                for (int c = 0; c < 4; c++)
                    acc[i][c] = fmaf(xr[i][j], wr[j][c], acc[i][c]);
    }
#pragma unroll
    for (int i = 0; i < 4; i++) {
        int grow = rowbase + rloc + 16 * i;
        if (grow < n) {
            float nf = nO[grow];
            ushort4 o;
            o.x = f2bf(acc[i][0] * nf); o.y = f2bf(acc[i][1] * nf);
            o.z = f2bf(acc[i][2] * nf); o.w = f2bf(acc[i][3] * nf);
            *(ushort4*)&h2[(size_t)grow * 32 + c0] = o;
        }
    }
}

// ---------------- agg2: wave/node, uint2 loads = 8 edges/VMEM ---------------
__global__ void k_agg32(const unsigned short* __restrict__ h,
                        const int* __restrict__ csrc,
                        const int* __restrict__ ostart, const int* __restrict__ oend,
                        const float* __restrict__ nI, const float* __restrict__ b2,
                        float* __restrict__ out, int n) {
    int node = blockIdx.x * 4 + (threadIdx.x >> 6);
    int lane = threadIdx.x & 63;
    if (node >= n) return;
    int s0 = ostart[node], s1 = oend[node];
    int sub = lane >> 3;
    int c4 = (lane & 7) * 4;
    float a0 = 0.f, a1 = 0.f, a2 = 0.f, a3 = 0.f;
    float d0 = 0.f, d1 = 0.f, d2 = 0.f, d3 = 0.f;
    int e = s0;
    for (; e + 15 < s1; e += 16) {               // 16 edges, 2 uint2 loads/lane
        int p0 = csrc[e + sub];
        int p1 = csrc[e + 8 + sub];
        uint2 u0 = *(const uint2*)&h[(size_t)p0 * 32 + c4];
        uint2 u1 = *(const uint2*)&h[(size_t)p1 * 32 + c4];
        a0 += __uint_as_float(u0.x << 16);
        a1 += __uint_as_float(u0.x & 0xFFFF0000u);
        a2 += __uint_as_float(u0.y << 16);
        a3 += __uint_as_float(u0.y & 0xFFFF0000u);
        d0 += __uint_as_float(u1.x << 16);
        d1 += __uint_as_float(u1.x & 0xFFFF0000u);
        d2 += __uint_as_float(u1.y << 16);
        d3 += __uint_as_float(u1.y & 0xFFFF0000u);
    }
    for (; e < s1; e += 8) {                     // tail, guarded
        if (e + sub < s1) {
            int p = csrc[e + sub];
            uint2 u = *(const uint2*)&h[(size_t)p * 32 + c4];
            a0 += __uint_as_float(u.x << 16);
            a1 += __uint_as_float(u.x & 0xFFFF0000u);
            a2 += __uint_as_float(u.y << 16);
            a3 += __uint_as_float(u.y & 0xFFFF0000u);
        }
    }
    a0 += d0; a1 += d1; a2 += d2; a3 += d3;
    a0 += __shfl(a0, lane ^ 8, 64);
    a1 += __shfl(a1, lane ^ 8, 64);
    a2 += __shfl(a2, lane ^ 8, 64);
    a3 += __shfl(a3, lane ^ 8, 64);
    a0 += __shfl(a0, lane ^ 16, 64);
    a1 += __shfl(a1, lane ^ 16, 64);
    a2 += __shfl(a2, lane ^ 16, 64);
    a3 += __shfl(a3, lane ^ 16, 64);
    a0 += __shfl(a0, lane ^ 32, 64);
    a1 += __shfl(a1, lane ^ 32, 64);
    a2 += __shfl(a2, lane ^ 32, 64);
    a3 += __shfl(a3, lane ^ 32, 64);
    if (sub == 0) {
        float ni = nI[node];
        float4 o;
        o.x = fmaf(a0, ni, b2[c4 + 0]);
        o.y = fmaf(a1, ni, b2[c4 + 1]);
        o.z = fmaf(a2, ni, b2[c4 + 2]);
        o.w = fmaf(a3, ni, b2[c4 + 3]);
        *(float4*)&out[(size_t)node * 32 + c4] = o;
    }
}

extern "C" void kernel_launch(void* const* d_in, const int* in_sizes, int n_in,
                              void* d_out, int out_size, void* d_ws, size_t ws_size,
                              hipStream_t stream) {
    const float* x   = (const float*)d_in[0];  // [N,128]
    const int*   src = (const int*)d_in[1];    // [E]
    const int*   dst = (const int*)d_in[2];    // [E]
    const float* W1  = (const float*)d_in[3];  // [128,64]
    const float* b1  = (const float*)d_in[4];  // [64]
    const float* W2  = (const float*)d_in[5];  // [64,32]
    const float* b2  = (const float*)d_in[6];  // [32]
    float* out = (float*)d_out;                // [N,32]

    const int N = in_sizes[0] / 128;           // 100000
    const int E = in_sizes[1];                 // 1600000
    const int NB = (N + BNODES - 1) / BNODES;  // 782 buckets
    const int NBLK = (E + CHUNK - 1) / CHUNK;  // 391 place blocks

    char* wsb = (char*)d_ws;
    float* nO     = (float*)wsb;  wsb += (size_t)N * 4;
    float* nI     = (float*)wsb;  wsb += (size_t)N * 4;
    int*   ostart = (int*)wsb;    wsb += (size_t)N * 4;
    int*   oend   = (int*)wsb;    wsb += (size_t)N * 4;
    int*   csrc   = (int*)wsb;    wsb += (size_t)NB * CAP * 4;     // 8.0 MB
    int*   offs   = (int*)wsb;    wsb += (size_t)NBLK * 801 * 4;   // 1.25 MB
    unsigned short* h1 = (unsigned short*)wsb;
                                  wsb += (size_t)N * 64 * 2;       // 12.8 MB bf16
    float* x2     = (float*)wsb;  wsb += (size_t)N * 64 * 4;       // 25.6 MB
    unsigned short* h2 = h1;      // h1 dead after k_agg64s
    // scratch aliased into x2 (dead before agg64s writes x2):
    int*   ebuf   = (int*)x2;                                      // 6.4 MB
    unsigned char* sbuf = (unsigned char*)(ebuf) + (size_t)E * 4;  // 1.6 MB
    int*   soffs  = (int*)(sbuf + (size_t)E);                      // 1.25 MB

    // CSR build — no memset, no global atomics anywhere
    k_place<<<NBLK, 1024, 0, stream>>>(src, dst, ebuf, sbuf, offs, soffs, E);
    k_sort2<<<NB, 1024, 0, stream>>>(ebuf, sbuf, offs, soffs, csrc,
                                     ostart, oend, nI, nO, N, NBLK);

    // layer 1 (h1 + x2 slice-major [4][N][16])
    k_gemm1<<<(N + 63) / 64, 256, 0, stream>>>(x, W1, nO, h1, N);
    k_agg64s<<<((N + 3) / 4) * 4, 256, 0, stream>>>(h1, csrc, ostart, oend,
                                                    nI, b1, x2, N);

    // layer 2
    k_gemm2<<<(N + 127) / 128, 256, 0, stream>>>(x2, W2, nO, h2, N);
    k_agg32<<<(N + 3) / 4, 256, 0, stream>>>(h2, csrc, ostart, oend, nI, b2, out, N);
}

// Round 4
// 293.657 us; speedup vs baseline: 1.3198x; 1.3198x over previous
//
#include <hip/hip_runtime.h>
#include <hip/hip_bf16.h>

// GNN: 2-layer GraphConv (DGL norm='both'), N=100000, E=1600000.
// Round 18: revert r17's slicing (FETCH 154->37MB but dur 56->142us: the agg
// is latency/issue-bound, not traffic-bound; 4x wave count paid 4x fixed
// overhead). Back to r16 row-major structure; upgrade both agg gathers
// uint2 -> uint4 (16B/lane): half the VMEM instructions/edge, 2x rows in
// flight per instruction, one fewer reduce stage. agg64: 8 edge-slots x
// 8 cols/lane, 16-edge main step (= mean degree -> exactly 1 iter).
// agg32: 16 edge-slots x 8 cols/lane, 16-edge step. CSR build (zero global
// atomics, block-local dual counting sort) unchanged from r16.

#define BSH 7                 // 128 nodes per bucket
#define BNODES 128
#define SRCMASK 0x1FFFF       // src < 131072
#define CAP 2560              // csrc bucket capacity (mean 2048, sigma~45)
#define CHUNK 4096            // edges per place-block (391 blocks)

__device__ __forceinline__ unsigned short f2bf(float f) {
    unsigned int u = __float_as_uint(f);
    return (unsigned short)((u + 0x7FFFu + ((u >> 16) & 1u)) >> 16);  // RNE
}

__device__ __forceinline__ float bflo(unsigned int u) {
    return __uint_as_float(u << 16);
}
__device__ __forceinline__ float bfhi(unsigned int u) {
    return __uint_as_float(u & 0xFFFF0000u);
}

// ---------------- place: block-local dual counting sort ---------------------
__global__ __launch_bounds__(1024) void k_place(const int* __restrict__ src,
        const int* __restrict__ dst, int* __restrict__ ebuf,
        unsigned char* __restrict__ sbuf, int* __restrict__ offs,
        int* __restrict__ soffs, int E) {
    __shared__ int lh[800], s[800];
    int t = threadIdx.x;
    int e0 = blockIdx.x * CHUNK;
    int e1 = min(e0 + CHUNK, E);
    if (t < 800) lh[t] = 0;
    __syncthreads();
    for (int i = e0 + t; i < e1; i += 1024) {
        atomicAdd(&lh[dst[i] >> BSH], 0x10000);
        atomicAdd(&lh[src[i] >> BSH], 1);
    }
    __syncthreads();
    if (t < 800) s[t] = lh[t];
    __syncthreads();
    for (int o = 1; o < 800; o <<= 1) {            // packed inclusive scan
        int u = (t < 800 && t >= o) ? s[t - o] : 0;
        __syncthreads();
        if (t < 800) s[t] += u;
        __syncthreads();
    }
    int obase = blockIdx.x * 801;
    if (t < 800) {
        int incl = s[t], c = lh[t];
        int bd = (incl >> 16) - (c >> 16);         // exclusive dst base
        int bs = (incl & 0xFFFF) - (c & 0xFFFF);   // exclusive src base
        offs[obase + t] = bd;
        soffs[obase + t] = bs;
        s[t] = (bd << 16) | bs;                    // packed cursors
    }
    if (t == 0) { offs[obase + 800] = e1 - e0; soffs[obase + 800] = e1 - e0; }
    __syncthreads();
    for (int i = e0 + t; i < e1; i += 1024) {
        int sv = src[i], d = dst[i];               // L2-hot from phase 1
        int pd = atomicAdd(&s[d >> BSH], 0x10000) >> 16;
        ebuf[e0 + pd] = sv | ((d & (BNODES - 1)) << 17);
        int ps = atomicAdd(&s[sv >> BSH], 1) & 0xFFFF;
        sbuf[e0 + ps] = (unsigned char)(sv & (BNODES - 1));
    }
}

// ---------------- sort2: segments -> CSR + nI + nO (no global atomics) ------
__global__ __launch_bounds__(1024) void k_sort2(const int* __restrict__ ebuf,
        const unsigned char* __restrict__ sbuf, const int* __restrict__ offs,
        const int* __restrict__ soffs, int* __restrict__ csrc,
        int* __restrict__ ostart, int* __restrict__ oend,
        float* __restrict__ nI, float* __restrict__ nO, int n, int NBLK) {
    __shared__ int cnt[BNODES], cur[BNODES], s[BNODES], scnt[BNODES];
    __shared__ int segst[400], segen[400], sst[400], sen[400];
    int t = threadIdx.x, b = blockIdx.x;
    if (t < NBLK) {
        segst[t] = t * CHUNK + offs[t * 801 + b];
        segen[t] = t * CHUNK + offs[t * 801 + b + 1];
        sst[t]   = t * CHUNK + soffs[t * 801 + b];
        sen[t]   = t * CHUNK + soffs[t * 801 + b + 1];
    }
    if (t < BNODES) { cnt[t] = 0; scnt[t] = 0; }
    __syncthreads();
    int grp = t >> 3, ln = t & 7;                  // 128 groups x 8 lanes
    for (int sg = grp; sg < NBLK; sg += 128) {
        int en = segen[sg];
        for (int i = segst[sg] + ln; i < en; i += 8)
            atomicAdd(&cnt[ebuf[i] >> 17], 1);
        int en2 = sen[sg];
        for (int i = sst[sg] + ln; i < en2; i += 8)
            atomicAdd(&scnt[sbuf[i]], 1);
    }
    __syncthreads();
    if (t < BNODES) s[t] = cnt[t];
    __syncthreads();
    for (int o = 1; o < BNODES; o <<= 1) {
        int u = (t < BNODES && t >= o) ? s[t - o] : 0;
        __syncthreads();
        if (t < BNODES) s[t] += u;
        __syncthreads();
    }
    if (t < BNODES) {
        int e0 = b * CAP;
        int st = e0 + s[t] - cnt[t];
        cur[t] = st;
        int g = b * BNODES + t;
        if (g < n) {
            ostart[g] = st;
            oend[g] = e0 + s[t];
            nI[g] = rsqrtf(fmaxf((float)cnt[t], 1.0f));
            nO[g] = rsqrtf(fmaxf((float)scnt[t], 1.0f));
        }
    }
    __syncthreads();
    for (int sg = grp; sg < NBLK; sg += 128) {
        int en = segen[sg];
        for (int i = segst[sg] + ln; i < en; i += 8) {
            int p = ebuf[i];                       // L2-hot from pass 1
            int pos = atomicAdd(&cur[p >> 17], 1);
            csrc[pos] = p & SRCMASK;
        }
    }
}

// ---------------- GEMM1: h1(bf16) = (x*nO) @ W1, 128->64 --------------------
__global__ __launch_bounds__(256) void k_gemm1(const float* __restrict__ x,
                        const float* __restrict__ W1, const float* __restrict__ nO,
                        unsigned short* __restrict__ h1, int n) {
    __shared__ float sX[64 * 132];
    __shared__ float sW[128 * 64];
    const int t = threadIdx.x;
    {
        const float4* W4 = (const float4*)W1;
        float4* sW4 = (float4*)sW;
#pragma unroll
        for (int i = 0; i < 8; i++) sW4[t + 256 * i] = W4[t + 256 * i];
    }
    const int rowbase = blockIdx.x * 64;
    {
        const float4* x4 = (const float4*)x;
        float4* sX4 = (float4*)sX;
#pragma unroll
        for (int i = 0; i < 8; i++) {
            int f = t + 256 * i;
            int row = f >> 5, kc = f & 31;
            int grow = rowbase + row;
            float4 v = make_float4(0.f, 0.f, 0.f, 0.f);
            if (grow < n) v = x4[(size_t)grow * 32 + kc];
            sX4[row * 33 + kc] = v;
        }
    }
    __syncthreads();
    const int lane = t & 63, wv = t >> 6;
    const int rg = lane >> 2, cg = lane & 3;
    const int c0 = wv * 16 + cg * 4;
    float acc[4][4] = {};
    for (int kk = 0; kk < 128; kk += 4) {
        float xr[4][4], wr[4][4];
#pragma unroll
        for (int i = 0; i < 4; i++)
            *(float4*)xr[i] = *(const float4*)&sX[(rg + 16 * i) * 132 + kk];
#pragma unroll
        for (int j = 0; j < 4; j++)
            *(float4*)wr[j] = *(const float4*)&sW[(kk + j) * 64 + c0];
#pragma unroll
        for (int j = 0; j < 4; j++)
#pragma unroll
            for (int i = 0; i < 4; i++)
#pragma unroll
                for (int c = 0; c < 4; c++)
                    acc[i][c] = fmaf(xr[i][j], wr[j][c], acc[i][c]);
    }
#pragma unroll
    for (int i = 0; i < 4; i++) {
        int grow = rowbase + rg + 16 * i;
        if (grow < n) {
            float nf = nO[grow];
            ushort4 o;
            o.x = f2bf(acc[i][0] * nf); o.y = f2bf(acc[i][1] * nf);
            o.z = f2bf(acc[i][2] * nf); o.w = f2bf(acc[i][3] * nf);
            *(ushort4*)&h1[(size_t)grow * 64 + c0] = o;
        }
    }
}

// ---------------- agg1: wave/node, uint4 = 8 rows in flight per VMEM --------
__global__ void k_agg64(const unsigned short* __restrict__ h,
                        const int* __restrict__ csrc,
                        const int* __restrict__ ostart, const int* __restrict__ oend,
                        const float* __restrict__ nI, const float* __restrict__ b1,
                        float* __restrict__ x2, int n) {
    int node = blockIdx.x * 4 + (threadIdx.x >> 6);
    int lane = threadIdx.x & 63;
    if (node >= n) return;
    int s0 = ostart[node], s1 = oend[node];
    int sub = lane >> 3;                         // 8 edge slots
    int c8 = (lane & 7) * 8;                     // 8 cols/lane (uint4 = 16B)
    float a[8] = {}, d[8] = {};
    int e = s0;
    for (; e + 15 < s1; e += 16) {               // 16 edges, 2 uint4/lane
        int p0 = csrc[e + sub];
        int p1 = csrc[e + 8 + sub];
        uint4 u0 = *(const uint4*)&h[(size_t)p0 * 64 + c8];
        uint4 u1 = *(const uint4*)&h[(size_t)p1 * 64 + c8];
        a[0] += bflo(u0.x); a[1] += bfhi(u0.x);
        a[2] += bflo(u0.y); a[3] += bfhi(u0.y);
        a[4] += bflo(u0.z); a[5] += bfhi(u0.z);
        a[6] += bflo(u0.w); a[7] += bfhi(u0.w);
        d[0] += bflo(u1.x); d[1] += bfhi(u1.x);
        d[2] += bflo(u1.y); d[3] += bfhi(u1.y);
        d[4] += bflo(u1.z); d[5] += bfhi(u1.z);
        d[6] += bflo(u1.w); d[7] += bfhi(u1.w);
    }
    for (; e < s1; e += 8) {                     // tail, guarded
        if (e + sub < s1) {
            int p = csrc[e + sub];
            uint4 u = *(const uint4*)&h[(size_t)p * 64 + c8];
            a[0] += bflo(u.x); a[1] += bfhi(u.x);
            a[2] += bflo(u.y); a[3] += bfhi(u.y);
            a[4] += bflo(u.z); a[5] += bfhi(u.z);
            a[6] += bflo(u.w); a[7] += bfhi(u.w);
        }
    }
#pragma unroll
    for (int i = 0; i < 8; i++) a[i] += d[i];
#pragma unroll
    for (int i = 0; i < 8; i++) {                // reduce over 8 subs
        a[i] += __shfl(a[i], lane ^ 8, 64);
        a[i] += __shfl(a[i], lane ^ 16, 64);
        a[i] += __shfl(a[i], lane ^ 32, 64);
    }
    if (sub == 0) {                              // lanes 0-7 -> 64 cols
        float ni = nI[node];
        float4 o0, o1;
        o0.x = fmaxf(fmaf(a[0], ni, b1[c8 + 0]), 0.f);
        o0.y = fmaxf(fmaf(a[1], ni, b1[c8 + 1]), 0.f);
        o0.z = fmaxf(fmaf(a[2], ni, b1[c8 + 2]), 0.f);
        o0.w = fmaxf(fmaf(a[3], ni, b1[c8 + 3]), 0.f);
        o1.x = fmaxf(fmaf(a[4], ni, b1[c8 + 4]), 0.f);
        o1.y = fmaxf(fmaf(a[5], ni, b1[c8 + 5]), 0.f);
        o1.z = fmaxf(fmaf(a[6], ni, b1[c8 + 6]), 0.f);
        o1.w = fmaxf(fmaf(a[7], ni, b1[c8 + 7]), 0.f);
        *(float4*)&x2[(size_t)node * 64 + c8] = o0;
        *(float4*)&x2[(size_t)node * 64 + c8 + 4] = o1;
    }
}

// ---------------- GEMM2: h2(bf16) = (x2*nO) @ W2, 64->32 --------------------
__global__ __launch_bounds__(256) void k_gemm2(const float* __restrict__ x2,
                        const float* __restrict__ W2, const float* __restrict__ nO,
                        unsigned short* __restrict__ h2, int n) {
    __shared__ float sX[128 * 68];
    __shared__ float sW[64 * 32];
    const int t = threadIdx.x;
    {
        const float4* W4 = (const float4*)W2;
        float4* sW4 = (float4*)sW;
#pragma unroll
        for (int i = 0; i < 2; i++) sW4[t + 256 * i] = W4[t + 256 * i];
    }
    const int rowbase = blockIdx.x * 128;
    {
        const float4* x4 = (const float4*)x2;
        float4* sX4 = (float4*)sX;
#pragma unroll
        for (int i = 0; i < 8; i++) {
            int f = t + 256 * i;
            int row = f >> 4, kc = f & 15;
            int grow = rowbase + row;
            float4 v = make_float4(0.f, 0.f, 0.f, 0.f);
            if (grow < n) v = x4[(size_t)grow * 16 + kc];
            sX4[row * 17 + kc] = v;
        }
    }
    __syncthreads();
    const int lane = t & 63, wv = t >> 6;
    const int whalf = wv >> 1, chalf = wv & 1;
    const int rg = lane >> 2, cg = lane & 3;
    const int c0 = chalf * 16 + cg * 4;
    const int rloc = whalf * 64 + rg;
    float acc[4][4] = {};
    for (int kk = 0; kk < 64; kk += 4) {
        float xr[4][4], wr[4][4];
#pragma unroll
        for (int i = 0; i < 4; i++)
            *(float4*)xr[i] = *(const float4*)&sX[(rloc + 16 * i) * 68 + kk];
#pragma unroll
        for (int j = 0; j < 4; j++)
            *(float4*)wr[j] = *(const float4*)&sW[(kk + j) * 32 + c0];
#pragma unroll
        for (int j = 0; j < 4; j++)
#pragma unroll
            for (int i = 0; i < 4; i++)
#pragma unroll
                for (int c = 0; c < 4; c++)
                    acc[i][c] = fmaf(xr[i][j], wr[j][c], acc[i][c]);
    }
#pragma unroll
    for (int i = 0; i < 4; i++) {
        int grow = rowbase + rloc + 16 * i;
        if (grow < n) {
            float nf = nO[grow];
            ushort4 o;
            o.x = f2bf(acc[i][0] * nf); o.y = f2bf(acc[i][1] * nf);
            o.z = f2bf(acc[i][2] * nf); o.w = f2bf(acc[i][3] * nf);
            *(ushort4*)&h2[(size_t)grow * 32 + c0] = o;
        }
    }
}

// ---------------- agg2: wave/node, uint4 = 16 rows in flight per VMEM -------
__global__ void k_agg32(const unsigned short* __restrict__ h,
                        const int* __restrict__ csrc,
                        const int* __restrict__ ostart, const int* __restrict__ oend,
                        const float* __restrict__ nI, const float* __restrict__ b2,
                        float* __restrict__ out, int n) {
    int node = blockIdx.x * 4 + (threadIdx.x >> 6);
    int lane = threadIdx.x & 63;
    if (node >= n) return;
    int s0 = ostart[node], s1 = oend[node];
    int sub = lane >> 2;                         // 16 edge slots
    int c8 = (lane & 3) * 8;                     // 8 cols/lane (uint4 = 16B)
    float a[8] = {};
    int e = s0;
    for (; e + 15 < s1; e += 16) {               // 16 edges, 1 uint4/lane
        int p = csrc[e + sub];
        uint4 u = *(const uint4*)&h[(size_t)p * 32 + c8];
        a[0] += bflo(u.x); a[1] += bfhi(u.x);
        a[2] += bflo(u.y); a[3] += bfhi(u.y);
        a[4] += bflo(u.z); a[5] += bfhi(u.z);
        a[6] += bflo(u.w); a[7] += bfhi(u.w);
    }
    for (; e < s1; e += 16) {                    // tail, guarded (<=1 pass)
        if (e + sub < s1) {
            int p = csrc[e + sub];
            uint4 u = *(const uint4*)&h[(size_t)p * 32 + c8];
            a[0] += bflo(u.x); a[1] += bfhi(u.x);
            a[2] += bflo(u.y); a[3] += bfhi(u.y);
            a[4] += bflo(u.z); a[5] += bfhi(u.z);
            a[6] += bflo(u.w); a[7] += bfhi(u.w);
        }
    }
#pragma unroll
    for (int i = 0; i < 8; i++) {                // reduce over 16 subs
        a[i] += __shfl(a[i], lane ^ 4, 64);
        a[i] += __shfl(a[i], lane ^ 8, 64);
        a[i] += __shfl(a[i], lane ^ 16, 64);
        a[i] += __shfl(a[i], lane ^ 32, 64);
    }
    if (sub == 0) {                              // lanes 0-3 -> 32 cols
        float ni = nI[node];
        float4 o0, o1;
        o0.x = fmaf(a[0], ni, b2[c8 + 0]);
        o0.y = fmaf(a[1], ni, b2[c8 + 1]);
        o0.z = fmaf(a[2], ni, b2[c8 + 2]);
        o0.w = fmaf(a[3], ni, b2[c8 + 3]);
        o1.x = fmaf(a[4], ni, b2[c8 + 4]);
        o1.y = fmaf(a[5], ni, b2[c8 + 5]);
        o1.z = fmaf(a[6], ni, b2[c8 + 6]);
        o1.w = fmaf(a[7], ni, b2[c8 + 7]);
        *(float4*)&out[(size_t)node * 32 + c8] = o0;
        *(float4*)&out[(size_t)node * 32 + c8 + 4] = o1;
    }
}

extern "C" void kernel_launch(void* const* d_in, const int* in_sizes, int n_in,
                              void* d_out, int out_size, void* d_ws, size_t ws_size,
                              hipStream_t stream) {
    const float* x   = (const float*)d_in[0];  // [N,128]
    const int*   src = (const int*)d_in[1];    // [E]
    const int*   dst = (const int*)d_in[2];    // [E]
    const float* W1  = (const float*)d_in[3];  // [128,64]
    const float* b1  = (const float*)d_in[4];  // [64]
    const float* W2  = (const float*)d_in[5];  // [64,32]
    const float* b2  = (const float*)d_in[6];  // [32]
    float* out = (float*)d_out;                // [N,32]

    const int N = in_sizes[0] / 128;           // 100000
    const int E = in_sizes[1];                 // 1600000
    const int NB = (N + BNODES - 1) / BNODES;  // 782 buckets
    const int NBLK = (E + CHUNK - 1) / CHUNK;  // 391 place blocks

    char* wsb = (char*)d_ws;
    float* nO     = (float*)wsb;  wsb += (size_t)N * 4;
    float* nI     = (float*)wsb;  wsb += (size_t)N * 4;
    int*   ostart = (int*)wsb;    wsb += (size_t)N * 4;
    int*   oend   = (int*)wsb;    wsb += (size_t)N * 4;
    int*   csrc   = (int*)wsb;    wsb += (size_t)NB * CAP * 4;     // 8.0 MB
    int*   offs   = (int*)wsb;    wsb += (size_t)NBLK * 801 * 4;   // 1.25 MB
    unsigned short* h1 = (unsigned short*)wsb;
                                  wsb += (size_t)N * 64 * 2;       // 12.8 MB bf16
    float* x2     = (float*)wsb;  wsb += (size_t)N * 64 * 4;       // 25.6 MB
    unsigned short* h2 = h1;      // h1 dead after k_agg64
    // scratch aliased into x2 (dead before agg64 writes x2):
    int*   ebuf   = (int*)x2;                                      // 6.4 MB
    unsigned char* sbuf = (unsigned char*)(ebuf) + (size_t)E * 4;  // 1.6 MB
    int*   soffs  = (int*)(sbuf + (size_t)E);                      // 1.25 MB

    // CSR build — no memset, no global atomics anywhere
    k_place<<<NBLK, 1024, 0, stream>>>(src, dst, ebuf, sbuf, offs, soffs, E);
    k_sort2<<<NB, 1024, 0, stream>>>(ebuf, sbuf, offs, soffs, csrc,
                                     ostart, oend, nI, nO, N, NBLK);

    // layer 1
    k_gemm1<<<(N + 63) / 64, 256, 0, stream>>>(x, W1, nO, h1, N);
    k_agg64<<<(N + 3) / 4, 256, 0, stream>>>(h1, csrc, ostart, oend, nI, b1, x2, N);

    // layer 2
    k_gemm2<<<(N + 127) / 128, 256, 0, stream>>>(x2, W2, nO, h2, N);
    k_agg32<<<(N + 3) / 4, 256, 0, stream>>>(h2, csrc, ostart, oend, nI, b2, out, N);
}